// Round 20
// baseline (279.456 us; speedup 1.0000x reference)
//
#include <hip/hip_runtime.h>
#include <hip/hip_bf16.h>
#include <stdint.h>

// B=4, Sq=Skv=1024, H=16, D=64, DM=1024, MRP=32
static constexpr int B_ = 4, S_ = 1024, H_ = 16, D_ = 64, DM_ = 1024;
static constexpr float SF_ = 45.254833221435546875f;
static constexpr float RCP_SF_ = 1.0f / SF_;
// log2(e)/SF folded: exp((t2-M)/SF) == exp2((t2-M)*KC)
static constexpr float KC_ = (float)(1.4426950408889634074 / 45.254833221435546875);

typedef unsigned short u16;
typedef __attribute__((ext_vector_type(8))) short bf16x8;
typedef __attribute__((ext_vector_type(4))) float f32x4;

#define MFMA_BF16 __builtin_amdgcn_mfma_f32_16x16x32_bf16

typedef const __attribute__((address_space(1))) void CGV;
typedef __attribute__((address_space(3))) void LDSV;
__device__ __forceinline__ void gload16(const void* g, void* l) {
  __builtin_amdgcn_global_load_lds((CGV*)g, (LDSV*)l, 16, 0, 0);
}

__device__ __forceinline__ float slot_scale(const unsigned* s) {
  return __uint_as_float(*s) / 127.0f + 1e-8f;  // absmax/127 + 1e-8, reference order
}
__device__ __forceinline__ float quantf(float x, float s) {
  return fminf(fmaxf(rintf(x / s), -127.f), 127.f);  // RNE like jnp.round
}
__device__ __forceinline__ u16 f2b(float x) {
  union { __hip_bfloat16 h; u16 u; } cv;
  cv.h = __float2bfloat16(x);
  return cv.u;
}
__device__ __forceinline__ float b2f(u16 u) { return __uint_as_float((unsigned)u << 16); }
__device__ __forceinline__ u16 qb16(float x, float s) { return f2b(quantf(x, s)); }

struct Ptr6 { const float* p[6]; int n4[6]; };

__global__ __launch_bounds__(256) void absmax6_kernel(Ptr6 a, unsigned* __restrict__ slots) {
  const int y = blockIdx.y;
  const float4* x4 = (const float4*)a.p[y];
  const int n4 = a.n4[y];
  float m = 0.f;
  for (int i = blockIdx.x * 256 + threadIdx.x; i < n4; i += gridDim.x * 256) {
    float4 v = x4[i];
    m = fmaxf(m, fmaxf(fmaxf(fabsf(v.x), fabsf(v.y)), fmaxf(fabsf(v.z), fabsf(v.w))));
  }
#pragma unroll
  for (int off = 32; off; off >>= 1) m = fmaxf(m, __shfl_xor(m, off));
  if ((threadIdx.x & 63) == 0) atomicMax(slots + y, __float_as_uint(m));
}

__device__ __forceinline__ void quant_body(const float* __restrict__ x, int n8, float s,
                                           u16* __restrict__ out) {
  for (int i = blockIdx.x * 256 + threadIdx.x; i < n8; i += gridDim.x * 256) {
    float4 v0 = *((const float4*)x + 2 * (size_t)i);
    float4 v1 = *((const float4*)x + 2 * (size_t)i + 1);
    int4 o;
    o.x = (int)qb16(v0.x, s) | ((int)qb16(v0.y, s) << 16);
    o.y = (int)qb16(v0.z, s) | ((int)qb16(v0.w, s) << 16);
    o.z = (int)qb16(v1.x, s) | ((int)qb16(v1.y, s) << 16);
    o.w = (int)qb16(v1.z, s) | ((int)qb16(v1.w, s) << 16);
    *((int4*)out + i) = o;
  }
}

__global__ __launch_bounds__(256) void quantize_bf16_kernel(const float* __restrict__ x, int n8,
                                                            const unsigned* __restrict__ slot,
                                                            u16* __restrict__ out) {
  quant_body(x, n8, slot_scale(slot), out);
}

// Merged input + weight quantization. z 0..1: activations; z 2..5: weight z-2 transposed.
struct QIW {
  const float* xq; const float* xkv; u16* xqo; u16* xkvo;
  const float* w[4]; u16* wt[4];
};
__global__ __launch_bounds__(256) void quantIW_kernel(QIW a, const unsigned* __restrict__ slots,
                                                      int n8) {
  __shared__ u16 t[64][72];
  const int z = blockIdx.z;
  const int tid = threadIdx.x;
  if (z < 2) {
    quant_body(z ? a.xkv : a.xq, n8, slot_scale(slots + z), z ? a.xkvo : a.xqo);
  } else {
    if (blockIdx.x >= 256) return;
    const int zz = z - 2;
    const float* w = a.w[zz];
    u16* wt = a.wt[zz];
    const float s = slot_scale(slots + 2 + zz);
    const int k0 = (blockIdx.x >> 4) * 64, n0 = (blockIdx.x & 15) * 64;
#pragma unroll
    for (int rr = 0; rr < 4; rr++) {
      const int row = (tid >> 4) + rr * 16;  // k
      const int col = (tid & 15) * 4;        // n
      float4 v = *(const float4*)&w[(size_t)(k0 + row) * DM_ + n0 + col];
      t[col + 0][row] = qb16(v.x, s);
      t[col + 1][row] = qb16(v.y, s);
      t[col + 2][row] = qb16(v.z, s);
      t[col + 3][row] = qb16(v.w, s);
    }
    __syncthreads();
    const int nr = tid >> 2, kc = (tid & 3) * 16;
    *(int4*)&wt[(size_t)(n0 + nr) * DM_ + k0 + kc] = *(const int4*)&t[nr][kc];
    *(int4*)&wt[(size_t)(n0 + nr) * DM_ + k0 + kc + 8] = *(const int4*)&t[nr][kc + 8];
  }
}

// Batched post-GEMM quantize: z=0 -> q panels, z=1 -> k panels, z=2 -> v transposed.
struct QP3 { const float* tf[3]; };
__global__ __launch_bounds__(256) void quantP3_kernel(QP3 a, const unsigned* __restrict__ slots,
                                                      u16* __restrict__ q_p, u16* __restrict__ k_p,
                                                      u16* __restrict__ vT) {
  __shared__ u16 t[64][72];
  const int z = blockIdx.z;
  const float s = slot_scale(slots + 6 + z);
  const int tid = threadIdx.x;
  if (z < 2) {
    const float* xf = a.tf[z];
    u16* xp = z ? k_p : q_p;
    const int st = blockIdx.x & 15, bh = blockIdx.x >> 4;
    const int b = bh >> 4, h = bh & 15;
    const int r = tid >> 2, seg = (tid & 3) * 16;
    const float* src = &xf[((size_t)(b * S_) + st * 64 + r) * DM_ + h * 64 + seg];
    u16 qv[16];
#pragma unroll
    for (int i = 0; i < 16; i += 4) {
      float4 v = *(const float4*)(src + i);
      qv[i] = qb16(v.x, s); qv[i + 1] = qb16(v.y, s);
      qv[i + 2] = qb16(v.z, s); qv[i + 3] = qb16(v.w, s);
    }
    u16* dst = &xp[((size_t)bh * S_ + st * 64 + r) * 64 + seg];
    *(int4*)dst = *(const int4*)&qv[0];
    *(int4*)(dst + 8) = *(const int4*)&qv[8];
  } else {
    const float* vf = a.tf[2];
    const int h = blockIdx.x >> 6, bt = blockIdx.x & 63;
    const int b = bt >> 4, kt = bt & 15;
    const int row = tid >> 2, seg = (tid & 3) * 16;
    const float* src = &vf[((size_t)(b * S_) + kt * 64 + row) * DM_ + h * 64 + seg];
    float4 v0 = *(const float4*)src;
    float4 v1 = *(const float4*)(src + 4);
    float4 v2 = *(const float4*)(src + 8);
    float4 v3 = *(const float4*)(src + 12);
    t[seg + 0][row] = qb16(v0.x, s);  t[seg + 1][row] = qb16(v0.y, s);
    t[seg + 2][row] = qb16(v0.z, s);  t[seg + 3][row] = qb16(v0.w, s);
    t[seg + 4][row] = qb16(v1.x, s);  t[seg + 5][row] = qb16(v1.y, s);
    t[seg + 6][row] = qb16(v1.z, s);  t[seg + 7][row] = qb16(v1.w, s);
    t[seg + 8][row] = qb16(v2.x, s);  t[seg + 9][row] = qb16(v2.y, s);
    t[seg + 10][row] = qb16(v2.z, s); t[seg + 11][row] = qb16(v2.w, s);
    t[seg + 12][row] = qb16(v3.x, s); t[seg + 13][row] = qb16(v3.y, s);
    t[seg + 14][row] = qb16(v3.z, s); t[seg + 15][row] = qb16(v3.w, s);
    __syncthreads();
    const int d = tid >> 2, s2 = (tid & 3) * 16;
    u16* dst = &vT[((size_t)(b * 16 + h) * 64 + d) * (size_t)S_ + kt * 64 + s2];
    *(int4*)dst = *(const int4*)&t[d][s2];
    *(int4*)(dst + 8) = *(const int4*)&t[d][s2 + 8];
  }
}

// Shared 128x128 GEMM body. C = exact-int(A[M,K].Bt[N,K]^T)*(sA*sB)+bias. M=4096, N=K=1024.
__device__ __forceinline__ void gemm_wide_body(
    const u16* __restrict__ A, const u16* __restrict__ Bt,
    const unsigned* __restrict__ slotA, const unsigned* __restrict__ slotB,
    const float* __restrict__ bias, float* __restrict__ C,
    unsigned* __restrict__ amax_out,
    u16 (*As)[128][64], u16 (*Bs)[128][64]) {
  const int N = DM_, K = DM_;
  const int id = blockIdx.x;                 // 0..255
  const int lin = (id & 7) * 32 + (id >> 3); // XCD-contiguous m-panels
  const int by = lin >> 3, bx = lin & 7;
  const int m0 = by * 128, n0 = bx * 128;
  const int tid = threadIdx.x, w = tid >> 6, lane = tid & 63;
  const int c = lane & 15, g = lane >> 4;
  const int wr = w >> 1, wc = w & 1;
  const int lr = lane >> 3, lc = lane & 7;
  const int schunk = (lc ^ lr) << 3;

  f32x4 acc[4][4] = {};

  auto stage = [&](int buf, int kc) {
#pragma unroll
    for (int p = 0; p < 4; ++p) {
      const int r0 = w * 32 + p * 8;
      gload16(&A[(size_t)(m0 + r0 + lr) * K + kc + schunk], &As[buf][r0][0]);
      gload16(&Bt[(size_t)(n0 + r0 + lr) * K + kc + schunk], &Bs[buf][r0][0]);
    }
  };

  stage(0, 0);
  __syncthreads();
  for (int kt = 0; kt < 16; ++kt) {
    const int buf = kt & 1;
    if (kt < 15) stage(buf ^ 1, (kt + 1) * 64);
#pragma unroll
    for (int ks = 0; ks < 2; ++ks) {
      const int rswz = ((ks * 4 + g) ^ (c & 7)) << 3;
      bf16x8 bv[4];
#pragma unroll
      for (int j = 0; j < 4; ++j)
        bv[j] = *(const bf16x8*)&Bs[buf][wc * 64 + j * 16 + c][rswz];
#pragma unroll
      for (int i = 0; i < 4; ++i) {
        bf16x8 av = *(const bf16x8*)&As[buf][wr * 64 + i * 16 + c][rswz];
#pragma unroll
        for (int j = 0; j < 4; ++j)
          acc[i][j] = MFMA_BF16(av, bv[j], acc[i][j], 0, 0, 0);
      }
    }
    __syncthreads();
  }

  const float sAB = slot_scale(slotA) * slot_scale(slotB);
  float am = 0.f;
#pragma unroll
  for (int i = 0; i < 4; ++i)
#pragma unroll
    for (int j = 0; j < 4; ++j)
#pragma unroll
      for (int reg = 0; reg < 4; ++reg) {
        const int m = m0 + wr * 64 + i * 16 + 4 * g + reg;
        const int nn = n0 + wc * 64 + j * 16 + c;
        const float val = __fadd_rn(__fmul_rn(acc[i][j][reg], sAB), bias[nn]);
        C[(size_t)m * N + nn] = val;
        am = fmaxf(am, fabsf(val));
      }
  if (amax_out) {
#pragma unroll
    for (int off = 32; off; off >>= 1) am = fmaxf(am, __shfl_xor(am, off));
    if (lane == 0) atomicMax(amax_out, __float_as_uint(am));
  }
}

// Batched 3-projection GEMM, 128x128 tile. grid dim3(256, 3).
struct G3 {
  const u16* A[3]; const u16* Bt[3]; const float* bias[3]; float* C[3];
};
__global__ __launch_bounds__(256) void gemm3_kernel(G3 a, unsigned* __restrict__ slots) {
  __shared__ u16 As[2][128][64];
  __shared__ u16 Bs[2][128][64];
  const int z = blockIdx.y;
  gemm_wide_body(a.A[z], a.Bt[z], slots + (z == 0 ? 0 : 1), slots + 2 + z,
                 a.bias[z], a.C[z], slots + 6 + z, As, Bs);
}

// Final Wo GEMM, same 128x128 body, grid 256.
__global__ __launch_bounds__(256) void gemm_wide_kernel(
    const u16* __restrict__ A, const u16* __restrict__ Bt,
    const unsigned* __restrict__ slotA, const unsigned* __restrict__ slotB,
    const float* __restrict__ bias, float* __restrict__ C) {
  __shared__ u16 As[2][128][64];
  __shared__ u16 Bs[2][128][64];
  gemm_wide_body(A, Bt, slotA, slotB, bias, C, nullptr, As, Bs);
}

// Fused attention. Change vs R19: SINGLE-buffer Ks/Vs (reg-prefetch, write after
// barrier, 2 barriers/chunk). LDS drops 76KB -> ~53KB => 3 blocks/CU (+50% TLP).
// Phase-split (scores u0,u1 then PV u0,u1 with per-u Pf) retained.
// Numerics bit-identical to R16/R18/R19.
__global__ __launch_bounds__(256, 3) void attn_kernel(
    const u16* __restrict__ qp_, const u16* __restrict__ kp_, const u16* __restrict__ vTb_,
    const unsigned* __restrict__ slots, const float* __restrict__ rel,
    float* __restrict__ ao, unsigned* __restrict__ amax_out) {
  __shared__ u16 Ks[64][64];
  __shared__ u16 Vs[64][64];
  __shared__ float Pf[4][2][16][68];   // [wave][u][q][kv]
  __shared__ float biasT[68];
  __shared__ float Mrow[4][2][16];
  __shared__ float Frow[4][2][16];
  __shared__ float Lrow[4][2][16];

  const int id = blockIdx.x;
  const int rX = id & 7, rest = id >> 3;
  const int qoct = rest & 7, bhi = rest >> 3;
  const int gbh = rX * 8 + bhi;
  const int h = gbh & 15, b = gbh >> 4;

  const int tid = threadIdx.x;
  const int w = tid >> 6, lane = tid & 63;
  const int c = lane & 15, g = lane >> 4;
  const int lr = lane >> 3, lc = lane & 7;
  const int schunk = (lc ^ lr) << 3;

  const float sqk = slot_scale(slots + 6) * slot_scale(slots + 7);
  const float sv = slot_scale(slots + 8);
  if (tid < 65) biasT[tid] = rel[tid * D_ + h];

  const size_t ppan = (size_t)gbh * S_ * 64;
  const size_t vpan = (size_t)gbh * 64 * (size_t)S_;

  const int qb2[2] = {qoct * 128 + w * 16, qoct * 128 + 64 + w * 16};
  bf16x8 qA0[2], qA1[2];
#pragma unroll
  for (int u = 0; u < 2; ++u) {
    const size_t qrow = ppan + (size_t)(qb2[u] + c) * 64;
    qA0[u] = *(const bf16x8*)&qp_[qrow + g * 8];
    qA1[u] = *(const bf16x8*)&qp_[qrow + 32 + g * 8];
  }

  int4 kreg[2], vreg[2];
  auto loadK = [&](int ch) {
#pragma unroll
    for (int p = 0; p < 2; ++p)
      kreg[p] = *(const int4*)&kp_[ppan + (size_t)(ch * 64 + w * 16 + p * 8 + lr) * 64 + schunk];
  };
  auto writeK = [&]() {
#pragma unroll
    for (int p = 0; p < 2; ++p)
      *(int4*)&Ks[w * 16 + p * 8 + lr][lc * 8] = kreg[p];
  };
  auto loadV = [&](int ch) {
#pragma unroll
    for (int p = 0; p < 2; ++p)
      vreg[p] = *(const int4*)&vTb_[vpan + (size_t)(w * 16 + p * 8 + lr) * S_ + ch * 64 + schunk];
  };
  auto writeV = [&]() {
#pragma unroll
    for (int p = 0; p < 2; ++p)
      *(int4*)&Vs[w * 16 + p * 8 + lr][lc * 8] = vreg[p];
  };

  float M2[2][4], m2k[2][4], lsc[2] = {0.f, 0.f};
  f32x4 oacc[2][4] = {};
#pragma unroll
  for (int u = 0; u < 2; ++u)
#pragma unroll
    for (int reg = 0; reg < 4; ++reg) {
      M2[u][reg] = -3.4e38f;
      m2k[u][reg] = -3.4e38f * KC_;
    }

  loadK(0);
  loadV(0);
  writeK();
  writeV();
  __syncthreads();
  const float b_lo = biasT[0], b_hi = biasT[64];

  for (int ch = 0; ch < 16; ++ch) {
    if (ch < 15) { loadK(ch + 1); loadV(ch + 1); }  // reg prefetch; hides under compute
    // ---- phase 1: scores for BOTH q-tiles (separate Pf[u] buffers) ----
#pragma unroll
    for (int u = 0; u < 2; ++u) {
      const int qbase = qb2[u];
      float mloc[4] = {-3.4e38f, -3.4e38f, -3.4e38f, -3.4e38f};
#pragma unroll
      for (int t = 0; t < 4; ++t) {
        f32x4 sacc = {0.f, 0.f, 0.f, 0.f};
        const int kr = t * 16 + c, sw = c & 7;
        bf16x8 k0 = *(const bf16x8*)&Ks[kr][(g ^ sw) << 3];
        bf16x8 k1 = *(const bf16x8*)&Ks[kr][((4 + g) ^ sw) << 3];
        sacc = MFMA_BF16(qA0[u], k0, sacc, 0, 0, 0);
        sacc = MFMA_BF16(qA1[u], k1, sacc, 0, 0, 0);
        const int kv0 = ch * 64 + t * 16;
        float bb[4];
        if (kv0 >= qbase + 47) {
          bb[0] = bb[1] = bb[2] = bb[3] = b_lo;
        } else if (qbase >= kv0 + 47) {
          bb[0] = bb[1] = bb[2] = bb[3] = b_hi;
        } else {
          const int jg = kv0 + c;
#pragma unroll
          for (int reg = 0; reg < 4; ++reg) {
            int dp = qbase + 4 * g + reg - jg + 32;
            dp = dp < 0 ? 0 : (dp > 64 ? 64 : dp);
            bb[reg] = biasT[dp];
          }
        }
        float* pw = &Pf[w][u][4 * g][t * 16 + c];
#pragma unroll
        for (int reg = 0; reg < 4; ++reg) {
          const float t2 = __fadd_rn(__fmul_rn(sacc[reg], sqk), bb[reg]);
          pw[reg * 68] = t2;
          mloc[reg] = fmaxf(mloc[reg], t2);
        }
      }
#pragma unroll
      for (int off = 1; off <= 8; off <<= 1)
#pragma unroll
        for (int reg = 0; reg < 4; ++reg)
          mloc[reg] = fmaxf(mloc[reg], __shfl_xor(mloc[reg], off));
      float f[4];
#pragma unroll
      for (int reg = 0; reg < 4; ++reg) {
        M2[u][reg] = fmaxf(M2[u][reg], mloc[reg]);
        const float mk = M2[u][reg] * KC_;
        f[reg] = exp2f(m2k[u][reg] - mk);
        m2k[u][reg] = mk;
      }
#pragma unroll
      for (int n = 0; n < 4; ++n)
#pragma unroll
        for (int reg = 0; reg < 4; ++reg) oacc[u][n][reg] *= f[reg];
      if (c < 4) {
        Mrow[w][u][4 * g + c] = m2k[u][c];
        Frow[w][u][4 * g + c] = f[c];
      }
    }
    // ---- phase 2: PV for BOTH q-tiles ----
#pragma unroll
    for (int u = 0; u < 2; ++u) {
      const float mkc = Mrow[w][u][c];
      lsc[u] = lsc[u] * Frow[w][u][c];
      float lacc = 0.f;
#pragma unroll
      for (int ks = 0; ks < 2; ++ks) {
        const float* pr = &Pf[w][u][c][ks * 32 + g * 8];
        float4 e0 = *(const float4*)pr;
        float4 e1 = *(const float4*)(pr + 4);
        float tv[8] = {e0.x, e0.y, e0.z, e0.w, e1.x, e1.y, e1.z, e1.w};
        bf16x8 ph, pm;
#pragma unroll
        for (int jj = 0; jj < 8; ++jj) {
          const float e = exp2f(fmaf(tv[jj], KC_, -mkc));
          lacc += e;
          const u16 hu = f2b(e);
          const float r1 = __fsub_rn(e, b2f(hu));
          const u16 mu = f2b(r1);
          ph[jj] = (short)hu;
          pm[jj] = (short)mu;
        }
#pragma unroll
        for (int n = 0; n < 4; ++n) {
          const int dd = 16 * n + c;
          bf16x8 vv = *(const bf16x8*)&Vs[dd][((ks * 4 + g) ^ (c & 7)) << 3];
          oacc[u][n] = MFMA_BF16(ph, vv, oacc[u][n], 0, 0, 0);
          oacc[u][n] = MFMA_BF16(pm, vv, oacc[u][n], 0, 0, 0);
        }
      }
      lsc[u] += lacc;
    }
    __syncthreads();                  // all waves done reading Ks/Vs
    if (ch < 15) { writeK(); writeV(); __syncthreads(); }
  }

#pragma unroll
  for (int u = 0; u < 2; ++u) {
    float t = lsc[u];
    t += __shfl_xor(t, 16);
    t += __shfl_xor(t, 32);
    if (g == 0) Lrow[w][u][c] = t;
  }

  float am = 0.f;
#pragma unroll
  for (int u = 0; u < 2; ++u) {
#pragma unroll
    for (int reg = 0; reg < 4; ++reg) {
      const float L = Lrow[w][u][4 * g + reg] + 1e-6f;
      const size_t orow = ((size_t)(b * S_) + qb2[u] + 4 * g + reg) * DM_ + h * 64;
#pragma unroll
      for (int n = 0; n < 4; ++n) {
        const float val = __fmul_rn(oacc[u][n][reg] / L, sv);
        ao[orow + n * 16 + c] = val;
        am = fmaxf(am, fabsf(val));
      }
    }
  }
#pragma unroll
  for (int off = 1; off <= 32; off <<= 1) am = fmaxf(am, __shfl_xor(am, off));
  if (lane == 0) atomicMax(amax_out, __float_as_uint(am));
}

extern "C" void kernel_launch(void* const* d_in, const int* in_sizes, int n_in,
                              void* d_out, int out_size, void* d_ws, size_t ws_size,
                              hipStream_t stream) {
  const float* inputs_q  = (const float*)d_in[0];
  const float* inputs_kv = (const float*)d_in[1];
  const float* Wq = (const float*)d_in[2];
  const float* bq = (const float*)d_in[3];
  const float* Wk = (const float*)d_in[4];
  const float* bk = (const float*)d_in[5];
  const float* Wv = (const float*)d_in[6];
  const float* bv = (const float*)d_in[7];
  const float* Wo = (const float*)d_in[8];
  const float* bo = (const float*)d_in[9];
  const float* rel = (const float*)d_in[10];
  float* out = (float*)d_out;

  char* ws = (char*)d_ws;
  constexpr size_t MB = 1024 * 1024;
  // slots: 0 sx_q, 1 sx_kv, 2 sWq, 3 sWk, 4 sWv, 5 sWo, 6 sq, 7 sk, 8 sv, 9 sao
  unsigned* slots = (unsigned*)ws;
  u16* xq_b  = (u16*)(ws + 1024);
  u16* xkv_b = (u16*)((char*)xq_b + 8 * MB);
  u16* wq_b  = (u16*)((char*)xkv_b + 8 * MB);
  u16* wk_b  = (u16*)((char*)wq_b + 2 * MB);
  u16* wv_b  = (u16*)((char*)wk_b + 2 * MB);
  u16* wo_b  = (u16*)((char*)wv_b + 2 * MB);
  u16* q_p   = (u16*)((char*)wo_b + 2 * MB);   // [bh][s][64] panels
  u16* k_p   = (u16*)((char*)q_p + 8 * MB);
  u16* vT_b  = (u16*)((char*)k_p + 8 * MB);    // [bh*64+d][kv]
  u16* ao_b  = (u16*)((char*)vT_b + 8 * MB);
  float* tf0 = (float*)((char*)ao_b + 8 * MB); // 16 MB each
  float* tf1 = (float*)((char*)tf0 + 16 * MB);
  float* tf2 = (float*)((char*)tf1 + 16 * MB);
  float* aof = tf0;                            // reuse tf0 for attn output
  (void)ws_size; (void)in_sizes; (void)n_in; (void)out_size;

  const int n4_x = (B_ * S_ * DM_) / 4, n4_w = (DM_ * DM_) / 4;
  const int n8_x = (B_ * S_ * DM_) / 8;

  hipMemsetAsync(slots, 0, 64, stream);

  Ptr6 a6;
  a6.p[0] = inputs_q;  a6.n4[0] = n4_x;
  a6.p[1] = inputs_kv; a6.n4[1] = n4_x;
  a6.p[2] = Wq; a6.n4[2] = n4_w;
  a6.p[3] = Wk; a6.n4[3] = n4_w;
  a6.p[4] = Wv; a6.n4[4] = n4_w;
  a6.p[5] = Wo; a6.n4[5] = n4_w;
  absmax6_kernel<<<dim3(128, 6), 256, 0, stream>>>(a6, slots);

  QIW qiw;
  qiw.xq = inputs_q; qiw.xkv = inputs_kv; qiw.xqo = xq_b; qiw.xkvo = xkv_b;
  qiw.w[0] = Wq; qiw.wt[0] = wq_b;
  qiw.w[1] = Wk; qiw.wt[1] = wk_b;
  qiw.w[2] = Wv; qiw.wt[2] = wv_b;
  qiw.w[3] = Wo; qiw.wt[3] = wo_b;
  quantIW_kernel<<<dim3(512, 1, 6), 256, 0, stream>>>(qiw, slots, n8_x);

  G3 g3;
  g3.A[0] = xq_b;  g3.Bt[0] = wq_b; g3.bias[0] = bq; g3.C[0] = tf0;
  g3.A[1] = xkv_b; g3.Bt[1] = wk_b; g3.bias[1] = bk; g3.C[1] = tf1;
  g3.A[2] = xkv_b; g3.Bt[2] = wv_b; g3.bias[2] = bv; g3.C[2] = tf2;
  gemm3_kernel<<<dim3(256, 3), 256, 0, stream>>>(g3, slots);

  QP3 qp3;
  qp3.tf[0] = tf0; qp3.tf[1] = tf1; qp3.tf[2] = tf2;
  quantP3_kernel<<<dim3(1024, 1, 3), 256, 0, stream>>>(qp3, slots, q_p, k_p, vT_b);

  attn_kernel<<<512, 256, 0, stream>>>(q_p, k_p, vT_b, slots, rel, aof, slots + 9);

  quantize_bf16_kernel<<<1024, 256, 0, stream>>>(aof, n8_x, slots + 9, ao_b);

  gemm_wide_kernel<<<256, 256, 0, stream>>>(ao_b, wo_b, slots + 9, slots + 5, bo, out);
}

// Round 21
// 259.257 us; speedup vs baseline: 1.0779x; 1.0779x over previous
//
#include <hip/hip_runtime.h>
#include <hip/hip_bf16.h>
#include <stdint.h>

// B=4, Sq=Skv=1024, H=16, D=64, DM=1024, MRP=32
static constexpr int B_ = 4, S_ = 1024, H_ = 16, D_ = 64, DM_ = 1024;
static constexpr float SF_ = 45.254833221435546875f;
static constexpr float RCP_SF_ = 1.0f / SF_;
// log2(e)/SF folded: exp((t2-M)/SF) == exp2((t2-M)*KC)
static constexpr float KC_ = (float)(1.4426950408889634074 / 45.254833221435546875);

typedef unsigned short u16;
typedef __attribute__((ext_vector_type(8))) short bf16x8;
typedef __attribute__((ext_vector_type(4))) float f32x4;

#define MFMA_BF16 __builtin_amdgcn_mfma_f32_16x16x32_bf16

typedef const __attribute__((address_space(1))) void CGV;
typedef __attribute__((address_space(3))) void LDSV;
__device__ __forceinline__ void gload16(const void* g, void* l) {
  __builtin_amdgcn_global_load_lds((CGV*)g, (LDSV*)l, 16, 0, 0);
}

__device__ __forceinline__ float slot_scale(const unsigned* s) {
  return __uint_as_float(*s) / 127.0f + 1e-8f;  // absmax/127 + 1e-8, reference order
}
__device__ __forceinline__ float quantf(float x, float s) {
  return fminf(fmaxf(rintf(x / s), -127.f), 127.f);  // RNE like jnp.round
}
__device__ __forceinline__ u16 f2b(float x) {
  union { __hip_bfloat16 h; u16 u; } cv;
  cv.h = __float2bfloat16(x);
  return cv.u;
}
__device__ __forceinline__ float b2f(u16 u) { return __uint_as_float((unsigned)u << 16); }
__device__ __forceinline__ u16 qb16(float x, float s) { return f2b(quantf(x, s)); }

struct Ptr6 { const float* p[6]; int n4[6]; };

__global__ __launch_bounds__(256) void absmax6_kernel(Ptr6 a, unsigned* __restrict__ slots) {
  const int y = blockIdx.y;
  const float4* x4 = (const float4*)a.p[y];
  const int n4 = a.n4[y];
  float m = 0.f;
  for (int i = blockIdx.x * 256 + threadIdx.x; i < n4; i += gridDim.x * 256) {
    float4 v = x4[i];
    m = fmaxf(m, fmaxf(fmaxf(fabsf(v.x), fabsf(v.y)), fmaxf(fabsf(v.z), fabsf(v.w))));
  }
#pragma unroll
  for (int off = 32; off; off >>= 1) m = fmaxf(m, __shfl_xor(m, off));
  if ((threadIdx.x & 63) == 0) atomicMax(slots + y, __float_as_uint(m));
}

__device__ __forceinline__ void quant_body(const float* __restrict__ x, int n8, float s,
                                           u16* __restrict__ out) {
  for (int i = blockIdx.x * 256 + threadIdx.x; i < n8; i += gridDim.x * 256) {
    float4 v0 = *((const float4*)x + 2 * (size_t)i);
    float4 v1 = *((const float4*)x + 2 * (size_t)i + 1);
    int4 o;
    o.x = (int)qb16(v0.x, s) | ((int)qb16(v0.y, s) << 16);
    o.y = (int)qb16(v0.z, s) | ((int)qb16(v0.w, s) << 16);
    o.z = (int)qb16(v1.x, s) | ((int)qb16(v1.y, s) << 16);
    o.w = (int)qb16(v1.z, s) | ((int)qb16(v1.w, s) << 16);
    *((int4*)out + i) = o;
  }
}

__global__ __launch_bounds__(256) void quantize_bf16_kernel(const float* __restrict__ x, int n8,
                                                            const unsigned* __restrict__ slot,
                                                            u16* __restrict__ out) {
  quant_body(x, n8, slot_scale(slot), out);
}

// Merged input + weight quantization. z 0..1: activations; z 2..5: weight z-2 transposed.
struct QIW {
  const float* xq; const float* xkv; u16* xqo; u16* xkvo;
  const float* w[4]; u16* wt[4];
};
__global__ __launch_bounds__(256) void quantIW_kernel(QIW a, const unsigned* __restrict__ slots,
                                                      int n8) {
  __shared__ u16 t[64][72];
  const int z = blockIdx.z;
  const int tid = threadIdx.x;
  if (z < 2) {
    quant_body(z ? a.xkv : a.xq, n8, slot_scale(slots + z), z ? a.xkvo : a.xqo);
  } else {
    if (blockIdx.x >= 256) return;
    const int zz = z - 2;
    const float* w = a.w[zz];
    u16* wt = a.wt[zz];
    const float s = slot_scale(slots + 2 + zz);
    const int k0 = (blockIdx.x >> 4) * 64, n0 = (blockIdx.x & 15) * 64;
#pragma unroll
    for (int rr = 0; rr < 4; rr++) {
      const int row = (tid >> 4) + rr * 16;  // k
      const int col = (tid & 15) * 4;        // n
      float4 v = *(const float4*)&w[(size_t)(k0 + row) * DM_ + n0 + col];
      t[col + 0][row] = qb16(v.x, s);
      t[col + 1][row] = qb16(v.y, s);
      t[col + 2][row] = qb16(v.z, s);
      t[col + 3][row] = qb16(v.w, s);
    }
    __syncthreads();
    const int nr = tid >> 2, kc = (tid & 3) * 16;
    *(int4*)&wt[(size_t)(n0 + nr) * DM_ + k0 + kc] = *(const int4*)&t[nr][kc];
    *(int4*)&wt[(size_t)(n0 + nr) * DM_ + k0 + kc + 8] = *(const int4*)&t[nr][kc + 8];
  }
}

// Batched post-GEMM quantize: z=0 -> q panels, z=1 -> k panels, z=2 -> v transposed.
struct QP3 { const float* tf[3]; };
__global__ __launch_bounds__(256) void quantP3_kernel(QP3 a, const unsigned* __restrict__ slots,
                                                      u16* __restrict__ q_p, u16* __restrict__ k_p,
                                                      u16* __restrict__ vT) {
  __shared__ u16 t[64][72];
  const int z = blockIdx.z;
  const float s = slot_scale(slots + 6 + z);
  const int tid = threadIdx.x;
  if (z < 2) {
    const float* xf = a.tf[z];
    u16* xp = z ? k_p : q_p;
    const int st = blockIdx.x & 15, bh = blockIdx.x >> 4;
    const int b = bh >> 4, h = bh & 15;
    const int r = tid >> 2, seg = (tid & 3) * 16;
    const float* src = &xf[((size_t)(b * S_) + st * 64 + r) * DM_ + h * 64 + seg];
    u16 qv[16];
#pragma unroll
    for (int i = 0; i < 16; i += 4) {
      float4 v = *(const float4*)(src + i);
      qv[i] = qb16(v.x, s); qv[i + 1] = qb16(v.y, s);
      qv[i + 2] = qb16(v.z, s); qv[i + 3] = qb16(v.w, s);
    }
    u16* dst = &xp[((size_t)bh * S_ + st * 64 + r) * 64 + seg];
    *(int4*)dst = *(const int4*)&qv[0];
    *(int4*)(dst + 8) = *(const int4*)&qv[8];
  } else {
    const float* vf = a.tf[2];
    const int h = blockIdx.x >> 6, bt = blockIdx.x & 63;
    const int b = bt >> 4, kt = bt & 15;
    const int row = tid >> 2, seg = (tid & 3) * 16;
    const float* src = &vf[((size_t)(b * S_) + kt * 64 + row) * DM_ + h * 64 + seg];
    float4 v0 = *(const float4*)src;
    float4 v1 = *(const float4*)(src + 4);
    float4 v2 = *(const float4*)(src + 8);
    float4 v3 = *(const float4*)(src + 12);
    t[seg + 0][row] = qb16(v0.x, s);  t[seg + 1][row] = qb16(v0.y, s);
    t[seg + 2][row] = qb16(v0.z, s);  t[seg + 3][row] = qb16(v0.w, s);
    t[seg + 4][row] = qb16(v1.x, s);  t[seg + 5][row] = qb16(v1.y, s);
    t[seg + 6][row] = qb16(v1.z, s);  t[seg + 7][row] = qb16(v1.w, s);
    t[seg + 8][row] = qb16(v2.x, s);  t[seg + 9][row] = qb16(v2.y, s);
    t[seg + 10][row] = qb16(v2.z, s); t[seg + 11][row] = qb16(v2.w, s);
    t[seg + 12][row] = qb16(v3.x, s); t[seg + 13][row] = qb16(v3.y, s);
    t[seg + 14][row] = qb16(v3.z, s); t[seg + 15][row] = qb16(v3.w, s);
    __syncthreads();
    const int d = tid >> 2, s2 = (tid & 3) * 16;
    u16* dst = &vT[((size_t)(b * 16 + h) * 64 + d) * (size_t)S_ + kt * 64 + s2];
    *(int4*)dst = *(const int4*)&t[d][s2];
    *(int4*)(dst + 8) = *(const int4*)&t[d][s2 + 8];
  }
}

// Shared 128x128 GEMM body. C = exact-int(A[M,K].Bt[N,K]^T)*(sA*sB)+bias. M=4096, N=K=1024.
__device__ __forceinline__ void gemm_wide_body(
    const u16* __restrict__ A, const u16* __restrict__ Bt,
    const unsigned* __restrict__ slotA, const unsigned* __restrict__ slotB,
    const float* __restrict__ bias, float* __restrict__ C,
    unsigned* __restrict__ amax_out,
    u16 (*As)[128][64], u16 (*Bs)[128][64]) {
  const int N = DM_, K = DM_;
  const int id = blockIdx.x;                 // 0..255
  const int lin = (id & 7) * 32 + (id >> 3); // XCD-contiguous m-panels
  const int by = lin >> 3, bx = lin & 7;
  const int m0 = by * 128, n0 = bx * 128;
  const int tid = threadIdx.x, w = tid >> 6, lane = tid & 63;
  const int c = lane & 15, g = lane >> 4;
  const int wr = w >> 1, wc = w & 1;
  const int lr = lane >> 3, lc = lane & 7;
  const int schunk = (lc ^ lr) << 3;

  f32x4 acc[4][4] = {};

  auto stage = [&](int buf, int kc) {
#pragma unroll
    for (int p = 0; p < 4; ++p) {
      const int r0 = w * 32 + p * 8;
      gload16(&A[(size_t)(m0 + r0 + lr) * K + kc + schunk], &As[buf][r0][0]);
      gload16(&Bt[(size_t)(n0 + r0 + lr) * K + kc + schunk], &Bs[buf][r0][0]);
    }
  };

  stage(0, 0);
  __syncthreads();
  for (int kt = 0; kt < 16; ++kt) {
    const int buf = kt & 1;
    if (kt < 15) stage(buf ^ 1, (kt + 1) * 64);
#pragma unroll
    for (int ks = 0; ks < 2; ++ks) {
      const int rswz = ((ks * 4 + g) ^ (c & 7)) << 3;
      bf16x8 bv[4];
#pragma unroll
      for (int j = 0; j < 4; ++j)
        bv[j] = *(const bf16x8*)&Bs[buf][wc * 64 + j * 16 + c][rswz];
#pragma unroll
      for (int i = 0; i < 4; ++i) {
        bf16x8 av = *(const bf16x8*)&As[buf][wr * 64 + i * 16 + c][rswz];
#pragma unroll
        for (int j = 0; j < 4; ++j)
          acc[i][j] = MFMA_BF16(av, bv[j], acc[i][j], 0, 0, 0);
      }
    }
    __syncthreads();
  }

  const float sAB = slot_scale(slotA) * slot_scale(slotB);
  float am = 0.f;
#pragma unroll
  for (int i = 0; i < 4; ++i)
#pragma unroll
    for (int j = 0; j < 4; ++j)
#pragma unroll
      for (int reg = 0; reg < 4; ++reg) {
        const int m = m0 + wr * 64 + i * 16 + 4 * g + reg;
        const int nn = n0 + wc * 64 + j * 16 + c;
        const float val = __fadd_rn(__fmul_rn(acc[i][j][reg], sAB), bias[nn]);
        C[(size_t)m * N + nn] = val;
        am = fmaxf(am, fabsf(val));
      }
  if (amax_out) {
#pragma unroll
    for (int off = 32; off; off >>= 1) am = fmaxf(am, __shfl_xor(am, off));
    if (lane == 0) atomicMax(amax_out, __float_as_uint(am));
  }
}

// Batched 3-projection GEMM, 128x128 tile. grid dim3(256, 3).
struct G3 {
  const u16* A[3]; const u16* Bt[3]; const float* bias[3]; float* C[3];
};
__global__ __launch_bounds__(256) void gemm3_kernel(G3 a, unsigned* __restrict__ slots) {
  __shared__ u16 As[2][128][64];
  __shared__ u16 Bs[2][128][64];
  const int z = blockIdx.y;
  gemm_wide_body(a.A[z], a.Bt[z], slots + (z == 0 ? 0 : 1), slots + 2 + z,
                 a.bias[z], a.C[z], slots + 6 + z, As, Bs);
}

// Final Wo GEMM, same 128x128 body, grid 256.
__global__ __launch_bounds__(256) void gemm_wide_kernel(
    const u16* __restrict__ A, const u16* __restrict__ Bt,
    const unsigned* __restrict__ slotA, const unsigned* __restrict__ slotB,
    const float* __restrict__ bias, float* __restrict__ C) {
  __shared__ u16 As[2][128][64];
  __shared__ u16 Bs[2][128][64];
  gemm_wide_body(A, Bt, slotA, slotB, bias, C, nullptr, As, Bs);
}

// Fused attention — R19 exact (best measured: 128us, VGPR 104, clean counters).
// Double-buffered Ks/Vs; per-u Pf buffers; phase-split scores(u0,u1) then PV(u0,u1).
__global__ __launch_bounds__(256, 3) void attn_kernel(
    const u16* __restrict__ qp_, const u16* __restrict__ kp_, const u16* __restrict__ vTb_,
    const unsigned* __restrict__ slots, const float* __restrict__ rel,
    float* __restrict__ ao, unsigned* __restrict__ amax_out) {
  __shared__ u16 Ks[2][64][64];
  __shared__ u16 Vs[2][64][64];
  __shared__ float Pf[4][2][16][68];   // [wave][u][q][kv]
  __shared__ float biasT[68];
  __shared__ float Mrow[4][2][16];
  __shared__ float Frow[4][2][16];
  __shared__ float Lrow[4][2][16];

  const int id = blockIdx.x;
  const int rX = id & 7, rest = id >> 3;
  const int qoct = rest & 7, bhi = rest >> 3;
  const int gbh = rX * 8 + bhi;
  const int h = gbh & 15, b = gbh >> 4;

  const int tid = threadIdx.x;
  const int w = tid >> 6, lane = tid & 63;
  const int c = lane & 15, g = lane >> 4;
  const int lr = lane >> 3, lc = lane & 7;
  const int schunk = (lc ^ lr) << 3;

  const float sqk = slot_scale(slots + 6) * slot_scale(slots + 7);
  const float sv = slot_scale(slots + 8);
  if (tid < 65) biasT[tid] = rel[tid * D_ + h];

  const size_t ppan = (size_t)gbh * S_ * 64;
  const size_t vpan = (size_t)gbh * 64 * (size_t)S_;

  const int qb2[2] = {qoct * 128 + w * 16, qoct * 128 + 64 + w * 16};
  bf16x8 qA0[2], qA1[2];
#pragma unroll
  for (int u = 0; u < 2; ++u) {
    const size_t qrow = ppan + (size_t)(qb2[u] + c) * 64;
    qA0[u] = *(const bf16x8*)&qp_[qrow + g * 8];
    qA1[u] = *(const bf16x8*)&qp_[qrow + 32 + g * 8];
  }

  int4 kreg[2], vreg[2];
  auto loadK = [&](int ch) {
#pragma unroll
    for (int p = 0; p < 2; ++p)
      kreg[p] = *(const int4*)&kp_[ppan + (size_t)(ch * 64 + w * 16 + p * 8 + lr) * 64 + schunk];
  };
  auto writeK = [&](int buf) {
#pragma unroll
    for (int p = 0; p < 2; ++p)
      *(int4*)&Ks[buf][w * 16 + p * 8 + lr][lc * 8] = kreg[p];
  };
  auto loadV = [&](int ch) {
#pragma unroll
    for (int p = 0; p < 2; ++p)
      vreg[p] = *(const int4*)&vTb_[vpan + (size_t)(w * 16 + p * 8 + lr) * S_ + ch * 64 + schunk];
  };
  auto writeV = [&](int buf) {
#pragma unroll
    for (int p = 0; p < 2; ++p)
      *(int4*)&Vs[buf][w * 16 + p * 8 + lr][lc * 8] = vreg[p];
  };

  float M2[2][4], m2k[2][4], lsc[2] = {0.f, 0.f};
  f32x4 oacc[2][4] = {};
#pragma unroll
  for (int u = 0; u < 2; ++u)
#pragma unroll
    for (int reg = 0; reg < 4; ++reg) {
      M2[u][reg] = -3.4e38f;
      m2k[u][reg] = -3.4e38f * KC_;
    }

  loadK(0);
  loadV(0);
  writeK(0);
  writeV(0);
  __syncthreads();
  const float b_lo = biasT[0], b_hi = biasT[64];

  for (int ch = 0; ch < 16; ++ch) {
    const int buf = ch & 1;
    if (ch < 15) { loadK(ch + 1); loadV(ch + 1); }
    // ---- phase 1: scores for BOTH q-tiles (separate Pf[u] buffers) ----
#pragma unroll
    for (int u = 0; u < 2; ++u) {
      const int qbase = qb2[u];
      float mloc[4] = {-3.4e38f, -3.4e38f, -3.4e38f, -3.4e38f};
#pragma unroll
      for (int t = 0; t < 4; ++t) {
        f32x4 sacc = {0.f, 0.f, 0.f, 0.f};
        const int kr = t * 16 + c, sw = c & 7;
        bf16x8 k0 = *(const bf16x8*)&Ks[buf][kr][(g ^ sw) << 3];
        bf16x8 k1 = *(const bf16x8*)&Ks[buf][kr][((4 + g) ^ sw) << 3];
        sacc = MFMA_BF16(qA0[u], k0, sacc, 0, 0, 0);
        sacc = MFMA_BF16(qA1[u], k1, sacc, 0, 0, 0);
        const int kv0 = ch * 64 + t * 16;
        float bb[4];
        if (kv0 >= qbase + 47) {
          bb[0] = bb[1] = bb[2] = bb[3] = b_lo;
        } else if (qbase >= kv0 + 47) {
          bb[0] = bb[1] = bb[2] = bb[3] = b_hi;
        } else {
          const int jg = kv0 + c;
#pragma unroll
          for (int reg = 0; reg < 4; ++reg) {
            int dp = qbase + 4 * g + reg - jg + 32;
            dp = dp < 0 ? 0 : (dp > 64 ? 64 : dp);
            bb[reg] = biasT[dp];
          }
        }
        float* pw = &Pf[w][u][4 * g][t * 16 + c];
#pragma unroll
        for (int reg = 0; reg < 4; ++reg) {
          const float t2 = __fadd_rn(__fmul_rn(sacc[reg], sqk), bb[reg]);
          pw[reg * 68] = t2;
          mloc[reg] = fmaxf(mloc[reg], t2);
        }
      }
#pragma unroll
      for (int off = 1; off <= 8; off <<= 1)
#pragma unroll
        for (int reg = 0; reg < 4; ++reg)
          mloc[reg] = fmaxf(mloc[reg], __shfl_xor(mloc[reg], off));
      float f[4];
#pragma unroll
      for (int reg = 0; reg < 4; ++reg) {
        M2[u][reg] = fmaxf(M2[u][reg], mloc[reg]);
        const float mk = M2[u][reg] * KC_;
        f[reg] = exp2f(m2k[u][reg] - mk);
        m2k[u][reg] = mk;
      }
#pragma unroll
      for (int n = 0; n < 4; ++n)
#pragma unroll
        for (int reg = 0; reg < 4; ++reg) oacc[u][n][reg] *= f[reg];
      if (c < 4) {
        Mrow[w][u][4 * g + c] = m2k[u][c];
        Frow[w][u][4 * g + c] = f[c];
      }
    }
    // ---- phase 2: PV for BOTH q-tiles ----
#pragma unroll
    for (int u = 0; u < 2; ++u) {
      const float mkc = Mrow[w][u][c];
      lsc[u] = lsc[u] * Frow[w][u][c];
      float lacc = 0.f;
#pragma unroll
      for (int ks = 0; ks < 2; ++ks) {
        const float* pr = &Pf[w][u][c][ks * 32 + g * 8];
        float4 e0 = *(const float4*)pr;
        float4 e1 = *(const float4*)(pr + 4);
        float tv[8] = {e0.x, e0.y, e0.z, e0.w, e1.x, e1.y, e1.z, e1.w};
        bf16x8 ph, pm;
#pragma unroll
        for (int jj = 0; jj < 8; ++jj) {
          const float e = exp2f(fmaf(tv[jj], KC_, -mkc));
          lacc += e;
          const u16 hu = f2b(e);
          const float r1 = __fsub_rn(e, b2f(hu));
          const u16 mu = f2b(r1);
          ph[jj] = (short)hu;
          pm[jj] = (short)mu;
        }
#pragma unroll
        for (int n = 0; n < 4; ++n) {
          const int dd = 16 * n + c;
          bf16x8 vv = *(const bf16x8*)&Vs[buf][dd][((ks * 4 + g) ^ (c & 7)) << 3];
          oacc[u][n] = MFMA_BF16(ph, vv, oacc[u][n], 0, 0, 0);
          oacc[u][n] = MFMA_BF16(pm, vv, oacc[u][n], 0, 0, 0);
        }
      }
      lsc[u] += lacc;
    }
    if (ch < 15) { writeK(buf ^ 1); writeV(buf ^ 1); }
    __syncthreads();
  }

#pragma unroll
  for (int u = 0; u < 2; ++u) {
    float t = lsc[u];
    t += __shfl_xor(t, 16);
    t += __shfl_xor(t, 32);
    if (g == 0) Lrow[w][u][c] = t;
  }

  float am = 0.f;
#pragma unroll
  for (int u = 0; u < 2; ++u) {
#pragma unroll
    for (int reg = 0; reg < 4; ++reg) {
      const float L = Lrow[w][u][4 * g + reg] + 1e-6f;
      const size_t orow = ((size_t)(b * S_) + qb2[u] + 4 * g + reg) * DM_ + h * 64;
#pragma unroll
      for (int n = 0; n < 4; ++n) {
        const float val = __fmul_rn(oacc[u][n][reg] / L, sv);
        ao[orow + n * 16 + c] = val;
        am = fmaxf(am, fabsf(val));
      }
    }
  }
#pragma unroll
  for (int off = 1; off <= 32; off <<= 1) am = fmaxf(am, __shfl_xor(am, off));
  if (lane == 0) atomicMax(amax_out, __float_as_uint(am));
}

extern "C" void kernel_launch(void* const* d_in, const int* in_sizes, int n_in,
                              void* d_out, int out_size, void* d_ws, size_t ws_size,
                              hipStream_t stream) {
  const float* inputs_q  = (const float*)d_in[0];
  const float* inputs_kv = (const float*)d_in[1];
  const float* Wq = (const float*)d_in[2];
  const float* bq = (const float*)d_in[3];
  const float* Wk = (const float*)d_in[4];
  const float* bk = (const float*)d_in[5];
  const float* Wv = (const float*)d_in[6];
  const float* bv = (const float*)d_in[7];
  const float* Wo = (const float*)d_in[8];
  const float* bo = (const float*)d_in[9];
  const float* rel = (const float*)d_in[10];
  float* out = (float*)d_out;

  char* ws = (char*)d_ws;
  constexpr size_t MB = 1024 * 1024;
  // slots: 0 sx_q, 1 sx_kv, 2 sWq, 3 sWk, 4 sWv, 5 sWo, 6 sq, 7 sk, 8 sv, 9 sao
  unsigned* slots = (unsigned*)ws;
  u16* xq_b  = (u16*)(ws + 1024);
  u16* xkv_b = (u16*)((char*)xq_b + 8 * MB);
  u16* wq_b  = (u16*)((char*)xkv_b + 8 * MB);
  u16* wk_b  = (u16*)((char*)wq_b + 2 * MB);
  u16* wv_b  = (u16*)((char*)wk_b + 2 * MB);
  u16* wo_b  = (u16*)((char*)wv_b + 2 * MB);
  u16* q_p   = (u16*)((char*)wo_b + 2 * MB);   // [bh][s][64] panels
  u16* k_p   = (u16*)((char*)q_p + 8 * MB);
  u16* vT_b  = (u16*)((char*)k_p + 8 * MB);    // [bh*64+d][kv]
  u16* ao_b  = (u16*)((char*)vT_b + 8 * MB);
  float* tf0 = (float*)((char*)ao_b + 8 * MB); // 16 MB each
  float* tf1 = (float*)((char*)tf0 + 16 * MB);
  float* tf2 = (float*)((char*)tf1 + 16 * MB);
  float* aof = tf0;                            // reuse tf0 for attn output
  (void)ws_size; (void)in_sizes; (void)n_in; (void)out_size;

  const int n4_x = (B_ * S_ * DM_) / 4, n4_w = (DM_ * DM_) / 4;
  const int n8_x = (B_ * S_ * DM_) / 8;

  hipMemsetAsync(slots, 0, 64, stream);

  Ptr6 a6;
  a6.p[0] = inputs_q;  a6.n4[0] = n4_x;
  a6.p[1] = inputs_kv; a6.n4[1] = n4_x;
  a6.p[2] = Wq; a6.n4[2] = n4_w;
  a6.p[3] = Wk; a6.n4[3] = n4_w;
  a6.p[4] = Wv; a6.n4[4] = n4_w;
  a6.p[5] = Wo; a6.n4[5] = n4_w;
  absmax6_kernel<<<dim3(128, 6), 256, 0, stream>>>(a6, slots);

  QIW qiw;
  qiw.xq = inputs_q; qiw.xkv = inputs_kv; qiw.xqo = xq_b; qiw.xkvo = xkv_b;
  qiw.w[0] = Wq; qiw.wt[0] = wq_b;
  qiw.w[1] = Wk; qiw.wt[1] = wk_b;
  qiw.w[2] = Wv; qiw.wt[2] = wv_b;
  qiw.w[3] = Wo; qiw.wt[3] = wo_b;
  quantIW_kernel<<<dim3(512, 1, 6), 256, 0, stream>>>(qiw, slots, n8_x);

  G3 g3;
  g3.A[0] = xq_b;  g3.Bt[0] = wq_b; g3.bias[0] = bq; g3.C[0] = tf0;
  g3.A[1] = xkv_b; g3.Bt[1] = wk_b; g3.bias[1] = bk; g3.C[1] = tf1;
  g3.A[2] = xkv_b; g3.Bt[2] = wv_b; g3.bias[2] = bv; g3.C[2] = tf2;
  gemm3_kernel<<<dim3(256, 3), 256, 0, stream>>>(g3, slots);

  QP3 qp3;
  qp3.tf[0] = tf0; qp3.tf[1] = tf1; qp3.tf[2] = tf2;
  quantP3_kernel<<<dim3(1024, 1, 3), 256, 0, stream>>>(qp3, slots, q_p, k_p, vT_b);

  attn_kernel<<<512, 256, 0, stream>>>(q_p, k_p, vT_b, slots, rel, aof, slots + 9);

  quantize_bf16_kernel<<<1024, 256, 0, stream>>>(aof, n8_x, slots + 9, ao_b);

  gemm_wide_kernel<<<256, 256, 0, stream>>>(ao_b, wo_b, slots + 9, slots + 5, bo, out);
}

// Round 22
// 258.081 us; speedup vs baseline: 1.0828x; 1.0046x over previous
//
#include <hip/hip_runtime.h>
#include <hip/hip_bf16.h>
#include <stdint.h>

// B=4, Sq=Skv=1024, H=16, D=64, DM=1024, MRP=32
static constexpr int B_ = 4, S_ = 1024, H_ = 16, D_ = 64, DM_ = 1024;
static constexpr float SF_ = 45.254833221435546875f;
static constexpr float RCP_SF_ = 1.0f / SF_;
// log2(e)/SF folded: exp((t2-M)/SF) == exp2((t2-M)*KC)
static constexpr float KC_ = (float)(1.4426950408889634074 / 45.254833221435546875);

typedef unsigned short u16;
typedef __attribute__((ext_vector_type(8))) short bf16x8;
typedef __attribute__((ext_vector_type(4))) float f32x4;

#define MFMA_BF16 __builtin_amdgcn_mfma_f32_16x16x32_bf16

typedef const __attribute__((address_space(1))) void CGV;
typedef __attribute__((address_space(3))) void LDSV;
__device__ __forceinline__ void gload16(const void* g, void* l) {
  __builtin_amdgcn_global_load_lds((CGV*)g, (LDSV*)l, 16, 0, 0);
}

__device__ __forceinline__ float slot_scale(const unsigned* s) {
  return __uint_as_float(*s) / 127.0f + 1e-8f;  // absmax/127 + 1e-8, reference order
}
__device__ __forceinline__ float quantf(float x, float s) {
  return fminf(fmaxf(rintf(x / s), -127.f), 127.f);  // RNE like jnp.round
}
__device__ __forceinline__ u16 f2b(float x) {
  union { __hip_bfloat16 h; u16 u; } cv;
  cv.h = __float2bfloat16(x);
  return cv.u;
}
__device__ __forceinline__ float b2f(u16 u) { return __uint_as_float((unsigned)u << 16); }
__device__ __forceinline__ u16 qb16(float x, float s) { return f2b(quantf(x, s)); }

struct Ptr6 { const float* p[6]; int n4[6]; };

__global__ __launch_bounds__(256) void absmax6_kernel(Ptr6 a, unsigned* __restrict__ slots) {
  const int y = blockIdx.y;
  const float4* x4 = (const float4*)a.p[y];
  const int n4 = a.n4[y];
  float m = 0.f;
  for (int i = blockIdx.x * 256 + threadIdx.x; i < n4; i += gridDim.x * 256) {
    float4 v = x4[i];
    m = fmaxf(m, fmaxf(fmaxf(fabsf(v.x), fabsf(v.y)), fmaxf(fabsf(v.z), fabsf(v.w))));
  }
#pragma unroll
  for (int off = 32; off; off >>= 1) m = fmaxf(m, __shfl_xor(m, off));
  if ((threadIdx.x & 63) == 0) atomicMax(slots + y, __float_as_uint(m));
}

__device__ __forceinline__ void quant_body(const float* __restrict__ x, int n8, float s,
                                           u16* __restrict__ out) {
  for (int i = blockIdx.x * 256 + threadIdx.x; i < n8; i += gridDim.x * 256) {
    float4 v0 = *((const float4*)x + 2 * (size_t)i);
    float4 v1 = *((const float4*)x + 2 * (size_t)i + 1);
    int4 o;
    o.x = (int)qb16(v0.x, s) | ((int)qb16(v0.y, s) << 16);
    o.y = (int)qb16(v0.z, s) | ((int)qb16(v0.w, s) << 16);
    o.z = (int)qb16(v1.x, s) | ((int)qb16(v1.y, s) << 16);
    o.w = (int)qb16(v1.z, s) | ((int)qb16(v1.w, s) << 16);
    *((int4*)out + i) = o;
  }
}

__global__ __launch_bounds__(256) void quantize_bf16_kernel(const float* __restrict__ x, int n8,
                                                            const unsigned* __restrict__ slot,
                                                            u16* __restrict__ out) {
  quant_body(x, n8, slot_scale(slot), out);
}

// Merged input + weight quantization. z 0..1: activations; z 2..5: weight z-2 transposed.
struct QIW {
  const float* xq; const float* xkv; u16* xqo; u16* xkvo;
  const float* w[4]; u16* wt[4];
};
__global__ __launch_bounds__(256) void quantIW_kernel(QIW a, const unsigned* __restrict__ slots,
                                                      int n8) {
  __shared__ u16 t[64][72];
  const int z = blockIdx.z;
  const int tid = threadIdx.x;
  if (z < 2) {
    quant_body(z ? a.xkv : a.xq, n8, slot_scale(slots + z), z ? a.xkvo : a.xqo);
  } else {
    if (blockIdx.x >= 256) return;
    const int zz = z - 2;
    const float* w = a.w[zz];
    u16* wt = a.wt[zz];
    const float s = slot_scale(slots + 2 + zz);
    const int k0 = (blockIdx.x >> 4) * 64, n0 = (blockIdx.x & 15) * 64;
#pragma unroll
    for (int rr = 0; rr < 4; rr++) {
      const int row = (tid >> 4) + rr * 16;  // k
      const int col = (tid & 15) * 4;        // n
      float4 v = *(const float4*)&w[(size_t)(k0 + row) * DM_ + n0 + col];
      t[col + 0][row] = qb16(v.x, s);
      t[col + 1][row] = qb16(v.y, s);
      t[col + 2][row] = qb16(v.z, s);
      t[col + 3][row] = qb16(v.w, s);
    }
    __syncthreads();
    const int nr = tid >> 2, kc = (tid & 3) * 16;
    *(int4*)&wt[(size_t)(n0 + nr) * DM_ + k0 + kc] = *(const int4*)&t[nr][kc];
    *(int4*)&wt[(size_t)(n0 + nr) * DM_ + k0 + kc + 8] = *(const int4*)&t[nr][kc + 8];
  }
}

// Batched post-GEMM quantize: z=0 -> q panels, z=1 -> k panels, z=2 -> v transposed.
struct QP3 { const float* tf[3]; };
__global__ __launch_bounds__(256) void quantP3_kernel(QP3 a, const unsigned* __restrict__ slots,
                                                      u16* __restrict__ q_p, u16* __restrict__ k_p,
                                                      u16* __restrict__ vT) {
  __shared__ u16 t[64][72];
  const int z = blockIdx.z;
  const float s = slot_scale(slots + 6 + z);
  const int tid = threadIdx.x;
  if (z < 2) {
    const float* xf = a.tf[z];
    u16* xp = z ? k_p : q_p;
    const int st = blockIdx.x & 15, bh = blockIdx.x >> 4;
    const int b = bh >> 4, h = bh & 15;
    const int r = tid >> 2, seg = (tid & 3) * 16;
    const float* src = &xf[((size_t)(b * S_) + st * 64 + r) * DM_ + h * 64 + seg];
    u16 qv[16];
#pragma unroll
    for (int i = 0; i < 16; i += 4) {
      float4 v = *(const float4*)(src + i);
      qv[i] = qb16(v.x, s); qv[i + 1] = qb16(v.y, s);
      qv[i + 2] = qb16(v.z, s); qv[i + 3] = qb16(v.w, s);
    }
    u16* dst = &xp[((size_t)bh * S_ + st * 64 + r) * 64 + seg];
    *(int4*)dst = *(const int4*)&qv[0];
    *(int4*)(dst + 8) = *(const int4*)&qv[8];
  } else {
    const float* vf = a.tf[2];
    const int h = blockIdx.x >> 6, bt = blockIdx.x & 63;
    const int b = bt >> 4, kt = bt & 15;
    const int row = tid >> 2, seg = (tid & 3) * 16;
    const float* src = &vf[((size_t)(b * S_) + kt * 64 + row) * DM_ + h * 64 + seg];
    float4 v0 = *(const float4*)src;
    float4 v1 = *(const float4*)(src + 4);
    float4 v2 = *(const float4*)(src + 8);
    float4 v3 = *(const float4*)(src + 12);
    t[seg + 0][row] = qb16(v0.x, s);  t[seg + 1][row] = qb16(v0.y, s);
    t[seg + 2][row] = qb16(v0.z, s);  t[seg + 3][row] = qb16(v0.w, s);
    t[seg + 4][row] = qb16(v1.x, s);  t[seg + 5][row] = qb16(v1.y, s);
    t[seg + 6][row] = qb16(v1.z, s);  t[seg + 7][row] = qb16(v1.w, s);
    t[seg + 8][row] = qb16(v2.x, s);  t[seg + 9][row] = qb16(v2.y, s);
    t[seg + 10][row] = qb16(v2.z, s); t[seg + 11][row] = qb16(v2.w, s);
    t[seg + 12][row] = qb16(v3.x, s); t[seg + 13][row] = qb16(v3.y, s);
    t[seg + 14][row] = qb16(v3.z, s); t[seg + 15][row] = qb16(v3.w, s);
    __syncthreads();
    const int d = tid >> 2, s2 = (tid & 3) * 16;
    u16* dst = &vT[((size_t)(b * 16 + h) * 64 + d) * (size_t)S_ + kt * 64 + s2];
    *(int4*)dst = *(const int4*)&t[d][s2];
    *(int4*)(dst + 8) = *(const int4*)&t[d][s2 + 8];
  }
}

// Shared 128x128 GEMM body. C = exact-int(A[M,K].Bt[N,K]^T)*(sA*sB)+bias. M=4096, N=K=1024.
__device__ __forceinline__ void gemm_wide_body(
    const u16* __restrict__ A, const u16* __restrict__ Bt,
    const unsigned* __restrict__ slotA, const unsigned* __restrict__ slotB,
    const float* __restrict__ bias, float* __restrict__ C,
    unsigned* __restrict__ amax_out,
    u16 (*As)[128][64], u16 (*Bs)[128][64]) {
  const int N = DM_, K = DM_;
  const int id = blockIdx.x;                 // 0..255
  const int lin = (id & 7) * 32 + (id >> 3); // XCD-contiguous m-panels
  const int by = lin >> 3, bx = lin & 7;
  const int m0 = by * 128, n0 = bx * 128;
  const int tid = threadIdx.x, w = tid >> 6, lane = tid & 63;
  const int c = lane & 15, g = lane >> 4;
  const int wr = w >> 1, wc = w & 1;
  const int lr = lane >> 3, lc = lane & 7;
  const int schunk = (lc ^ lr) << 3;

  f32x4 acc[4][4] = {};

  auto stage = [&](int buf, int kc) {
#pragma unroll
    for (int p = 0; p < 4; ++p) {
      const int r0 = w * 32 + p * 8;
      gload16(&A[(size_t)(m0 + r0 + lr) * K + kc + schunk], &As[buf][r0][0]);
      gload16(&Bt[(size_t)(n0 + r0 + lr) * K + kc + schunk], &Bs[buf][r0][0]);
    }
  };

  stage(0, 0);
  __syncthreads();
  for (int kt = 0; kt < 16; ++kt) {
    const int buf = kt & 1;
    if (kt < 15) stage(buf ^ 1, (kt + 1) * 64);
#pragma unroll
    for (int ks = 0; ks < 2; ++ks) {
      const int rswz = ((ks * 4 + g) ^ (c & 7)) << 3;
      bf16x8 bv[4];
#pragma unroll
      for (int j = 0; j < 4; ++j)
        bv[j] = *(const bf16x8*)&Bs[buf][wc * 64 + j * 16 + c][rswz];
#pragma unroll
      for (int i = 0; i < 4; ++i) {
        bf16x8 av = *(const bf16x8*)&As[buf][wr * 64 + i * 16 + c][rswz];
#pragma unroll
        for (int j = 0; j < 4; ++j)
          acc[i][j] = MFMA_BF16(av, bv[j], acc[i][j], 0, 0, 0);
      }
    }
    __syncthreads();
  }

  const float sAB = slot_scale(slotA) * slot_scale(slotB);
  float am = 0.f;
#pragma unroll
  for (int i = 0; i < 4; ++i)
#pragma unroll
    for (int j = 0; j < 4; ++j)
#pragma unroll
      for (int reg = 0; reg < 4; ++reg) {
        const int m = m0 + wr * 64 + i * 16 + 4 * g + reg;
        const int nn = n0 + wc * 64 + j * 16 + c;
        const float val = __fadd_rn(__fmul_rn(acc[i][j][reg], sAB), bias[nn]);
        C[(size_t)m * N + nn] = val;
        am = fmaxf(am, fabsf(val));
      }
  if (amax_out) {
#pragma unroll
    for (int off = 32; off; off >>= 1) am = fmaxf(am, __shfl_xor(am, off));
    if (lane == 0) atomicMax(amax_out, __float_as_uint(am));
  }
}

// Batched 3-projection GEMM, 128x128 tile. grid dim3(256, 3).
struct G3 {
  const u16* A[3]; const u16* Bt[3]; const float* bias[3]; float* C[3];
};
__global__ __launch_bounds__(256) void gemm3_kernel(G3 a, unsigned* __restrict__ slots) {
  __shared__ u16 As[2][128][64];
  __shared__ u16 Bs[2][128][64];
  const int z = blockIdx.y;
  gemm_wide_body(a.A[z], a.Bt[z], slots + (z == 0 ? 0 : 1), slots + 2 + z,
                 a.bias[z], a.C[z], slots + 6 + z, As, Bs);
}

// Final Wo GEMM, same 128x128 body, grid 256.
__global__ __launch_bounds__(256) void gemm_wide_kernel(
    const u16* __restrict__ A, const u16* __restrict__ Bt,
    const unsigned* __restrict__ slotA, const unsigned* __restrict__ slotB,
    const float* __restrict__ bias, float* __restrict__ C) {
  __shared__ u16 As[2][128][64];
  __shared__ u16 Bs[2][128][64];
  gemm_wide_body(A, Bt, slotA, slotB, bias, C, nullptr, As, Bs);
}

// Fused attention — R19/R21 structure, launch bounds RELAXED to (256):
// LDS (77.8KB) pins residency at 2 blocks/CU regardless of VGPR (up to 256/wave
// still sustains 2 waves/SIMD), so the (256,3) reg cap only constrained the
// allocator. Uncapped lets the scheduler keep more values live across phases.
__global__ __launch_bounds__(256) void attn_kernel(
    const u16* __restrict__ qp_, const u16* __restrict__ kp_, const u16* __restrict__ vTb_,
    const unsigned* __restrict__ slots, const float* __restrict__ rel,
    float* __restrict__ ao, unsigned* __restrict__ amax_out) {
  __shared__ u16 Ks[2][64][64];
  __shared__ u16 Vs[2][64][64];
  __shared__ float Pf[4][2][16][68];   // [wave][u][q][kv]
  __shared__ float biasT[68];
  __shared__ float Mrow[4][2][16];
  __shared__ float Frow[4][2][16];
  __shared__ float Lrow[4][2][16];

  const int id = blockIdx.x;
  const int rX = id & 7, rest = id >> 3;
  const int qoct = rest & 7, bhi = rest >> 3;
  const int gbh = rX * 8 + bhi;
  const int h = gbh & 15, b = gbh >> 4;

  const int tid = threadIdx.x;
  const int w = tid >> 6, lane = tid & 63;
  const int c = lane & 15, g = lane >> 4;
  const int lr = lane >> 3, lc = lane & 7;
  const int schunk = (lc ^ lr) << 3;

  const float sqk = slot_scale(slots + 6) * slot_scale(slots + 7);
  const float sv = slot_scale(slots + 8);
  if (tid < 65) biasT[tid] = rel[tid * D_ + h];

  const size_t ppan = (size_t)gbh * S_ * 64;
  const size_t vpan = (size_t)gbh * 64 * (size_t)S_;

  const int qb2[2] = {qoct * 128 + w * 16, qoct * 128 + 64 + w * 16};
  bf16x8 qA0[2], qA1[2];
#pragma unroll
  for (int u = 0; u < 2; ++u) {
    const size_t qrow = ppan + (size_t)(qb2[u] + c) * 64;
    qA0[u] = *(const bf16x8*)&qp_[qrow + g * 8];
    qA1[u] = *(const bf16x8*)&qp_[qrow + 32 + g * 8];
  }

  int4 kreg[2], vreg[2];
  auto loadK = [&](int ch) {
#pragma unroll
    for (int p = 0; p < 2; ++p)
      kreg[p] = *(const int4*)&kp_[ppan + (size_t)(ch * 64 + w * 16 + p * 8 + lr) * 64 + schunk];
  };
  auto writeK = [&](int buf) {
#pragma unroll
    for (int p = 0; p < 2; ++p)
      *(int4*)&Ks[buf][w * 16 + p * 8 + lr][lc * 8] = kreg[p];
  };
  auto loadV = [&](int ch) {
#pragma unroll
    for (int p = 0; p < 2; ++p)
      vreg[p] = *(const int4*)&vTb_[vpan + (size_t)(w * 16 + p * 8 + lr) * S_ + ch * 64 + schunk];
  };
  auto writeV = [&](int buf) {
#pragma unroll
    for (int p = 0; p < 2; ++p)
      *(int4*)&Vs[buf][w * 16 + p * 8 + lr][lc * 8] = vreg[p];
  };

  float M2[2][4], m2k[2][4], lsc[2] = {0.f, 0.f};
  f32x4 oacc[2][4] = {};
#pragma unroll
  for (int u = 0; u < 2; ++u)
#pragma unroll
    for (int reg = 0; reg < 4; ++reg) {
      M2[u][reg] = -3.4e38f;
      m2k[u][reg] = -3.4e38f * KC_;
    }

  loadK(0);
  loadV(0);
  writeK(0);
  writeV(0);
  __syncthreads();
  const float b_lo = biasT[0], b_hi = biasT[64];

  for (int ch = 0; ch < 16; ++ch) {
    const int buf = ch & 1;
    if (ch < 15) { loadK(ch + 1); loadV(ch + 1); }
    // ---- phase 1: scores for BOTH q-tiles (separate Pf[u] buffers) ----
#pragma unroll
    for (int u = 0; u < 2; ++u) {
      const int qbase = qb2[u];
      float mloc[4] = {-3.4e38f, -3.4e38f, -3.4e38f, -3.4e38f};
#pragma unroll
      for (int t = 0; t < 4; ++t) {
        f32x4 sacc = {0.f, 0.f, 0.f, 0.f};
        const int kr = t * 16 + c, sw = c & 7;
        bf16x8 k0 = *(const bf16x8*)&Ks[buf][kr][(g ^ sw) << 3];
        bf16x8 k1 = *(const bf16x8*)&Ks[buf][kr][((4 + g) ^ sw) << 3];
        sacc = MFMA_BF16(qA0[u], k0, sacc, 0, 0, 0);
        sacc = MFMA_BF16(qA1[u], k1, sacc, 0, 0, 0);
        const int kv0 = ch * 64 + t * 16;
        float bb[4];
        if (kv0 >= qbase + 47) {
          bb[0] = bb[1] = bb[2] = bb[3] = b_lo;
        } else if (qbase >= kv0 + 47) {
          bb[0] = bb[1] = bb[2] = bb[3] = b_hi;
        } else {
          const int jg = kv0 + c;
#pragma unroll
          for (int reg = 0; reg < 4; ++reg) {
            int dp = qbase + 4 * g + reg - jg + 32;
            dp = dp < 0 ? 0 : (dp > 64 ? 64 : dp);
            bb[reg] = biasT[dp];
          }
        }
        float* pw = &Pf[w][u][4 * g][t * 16 + c];
#pragma unroll
        for (int reg = 0; reg < 4; ++reg) {
          const float t2 = __fadd_rn(__fmul_rn(sacc[reg], sqk), bb[reg]);
          pw[reg * 68] = t2;
          mloc[reg] = fmaxf(mloc[reg], t2);
        }
      }
#pragma unroll
      for (int off = 1; off <= 8; off <<= 1)
#pragma unroll
        for (int reg = 0; reg < 4; ++reg)
          mloc[reg] = fmaxf(mloc[reg], __shfl_xor(mloc[reg], off));
      float f[4];
#pragma unroll
      for (int reg = 0; reg < 4; ++reg) {
        M2[u][reg] = fmaxf(M2[u][reg], mloc[reg]);
        const float mk = M2[u][reg] * KC_;
        f[reg] = exp2f(m2k[u][reg] - mk);
        m2k[u][reg] = mk;
      }
#pragma unroll
      for (int n = 0; n < 4; ++n)
#pragma unroll
        for (int reg = 0; reg < 4; ++reg) oacc[u][n][reg] *= f[reg];
      if (c < 4) {
        Mrow[w][u][4 * g + c] = m2k[u][c];
        Frow[w][u][4 * g + c] = f[c];
      }
    }
    // ---- phase 2: PV for BOTH q-tiles ----
#pragma unroll
    for (int u = 0; u < 2; ++u) {
      const float mkc = Mrow[w][u][c];
      lsc[u] = lsc[u] * Frow[w][u][c];
      float lacc = 0.f;
#pragma unroll
      for (int ks = 0; ks < 2; ++ks) {
        const float* pr = &Pf[w][u][c][ks * 32 + g * 8];
        float4 e0 = *(const float4*)pr;
        float4 e1 = *(const float4*)(pr + 4);
        float tv[8] = {e0.x, e0.y, e0.z, e0.w, e1.x, e1.y, e1.z, e1.w};
        bf16x8 ph, pm;
#pragma unroll
        for (int jj = 0; jj < 8; ++jj) {
          const float e = exp2f(fmaf(tv[jj], KC_, -mkc));
          lacc += e;
          const u16 hu = f2b(e);
          const float r1 = __fsub_rn(e, b2f(hu));
          const u16 mu = f2b(r1);
          ph[jj] = (short)hu;
          pm[jj] = (short)mu;
        }
#pragma unroll
        for (int n = 0; n < 4; ++n) {
          const int dd = 16 * n + c;
          bf16x8 vv = *(const bf16x8*)&Vs[buf][dd][((ks * 4 + g) ^ (c & 7)) << 3];
          oacc[u][n] = MFMA_BF16(ph, vv, oacc[u][n], 0, 0, 0);
          oacc[u][n] = MFMA_BF16(pm, vv, oacc[u][n], 0, 0, 0);
        }
      }
      lsc[u] += lacc;
    }
    if (ch < 15) { writeK(buf ^ 1); writeV(buf ^ 1); }
    __syncthreads();
  }

#pragma unroll
  for (int u = 0; u < 2; ++u) {
    float t = lsc[u];
    t += __shfl_xor(t, 16);
    t += __shfl_xor(t, 32);
    if (g == 0) Lrow[w][u][c] = t;
  }

  float am = 0.f;
#pragma unroll
  for (int u = 0; u < 2; ++u) {
#pragma unroll
    for (int reg = 0; reg < 4; ++reg) {
      const float L = Lrow[w][u][4 * g + reg] + 1e-6f;
      const size_t orow = ((size_t)(b * S_) + qb2[u] + 4 * g + reg) * DM_ + h * 64;
#pragma unroll
      for (int n = 0; n < 4; ++n) {
        const float val = __fmul_rn(oacc[u][n][reg] / L, sv);
        ao[orow + n * 16 + c] = val;
        am = fmaxf(am, fabsf(val));
      }
    }
  }
#pragma unroll
  for (int off = 1; off <= 32; off <<= 1) am = fmaxf(am, __shfl_xor(am, off));
  if (lane == 0) atomicMax(amax_out, __float_as_uint(am));
}

extern "C" void kernel_launch(void* const* d_in, const int* in_sizes, int n_in,
                              void* d_out, int out_size, void* d_ws, size_t ws_size,
                              hipStream_t stream) {
  const float* inputs_q  = (const float*)d_in[0];
  const float* inputs_kv = (const float*)d_in[1];
  const float* Wq = (const float*)d_in[2];
  const float* bq = (const float*)d_in[3];
  const float* Wk = (const float*)d_in[4];
  const float* bk = (const float*)d_in[5];
  const float* Wv = (const float*)d_in[6];
  const float* bv = (const float*)d_in[7];
  const float* Wo = (const float*)d_in[8];
  const float* bo = (const float*)d_in[9];
  const float* rel = (const float*)d_in[10];
  float* out = (float*)d_out;

  char* ws = (char*)d_ws;
  constexpr size_t MB = 1024 * 1024;
  // slots: 0 sx_q, 1 sx_kv, 2 sWq, 3 sWk, 4 sWv, 5 sWo, 6 sq, 7 sk, 8 sv, 9 sao
  unsigned* slots = (unsigned*)ws;
  u16* xq_b  = (u16*)(ws + 1024);
  u16* xkv_b = (u16*)((char*)xq_b + 8 * MB);
  u16* wq_b  = (u16*)((char*)xkv_b + 8 * MB);
  u16* wk_b  = (u16*)((char*)wq_b + 2 * MB);
  u16* wv_b  = (u16*)((char*)wk_b + 2 * MB);
  u16* wo_b  = (u16*)((char*)wv_b + 2 * MB);
  u16* q_p   = (u16*)((char*)wo_b + 2 * MB);   // [bh][s][64] panels
  u16* k_p   = (u16*)((char*)q_p + 8 * MB);
  u16* vT_b  = (u16*)((char*)k_p + 8 * MB);    // [bh*64+d][kv]
  u16* ao_b  = (u16*)((char*)vT_b + 8 * MB);
  float* tf0 = (float*)((char*)ao_b + 8 * MB); // 16 MB each
  float* tf1 = (float*)((char*)tf0 + 16 * MB);
  float* tf2 = (float*)((char*)tf1 + 16 * MB);
  float* aof = tf0;                            // reuse tf0 for attn output
  (void)ws_size; (void)in_sizes; (void)n_in; (void)out_size;

  const int n4_x = (B_ * S_ * DM_) / 4, n4_w = (DM_ * DM_) / 4;
  const int n8_x = (B_ * S_ * DM_) / 8;

  hipMemsetAsync(slots, 0, 64, stream);

  Ptr6 a6;
  a6.p[0] = inputs_q;  a6.n4[0] = n4_x;
  a6.p[1] = inputs_kv; a6.n4[1] = n4_x;
  a6.p[2] = Wq; a6.n4[2] = n4_w;
  a6.p[3] = Wk; a6.n4[3] = n4_w;
  a6.p[4] = Wv; a6.n4[4] = n4_w;
  a6.p[5] = Wo; a6.n4[5] = n4_w;
  absmax6_kernel<<<dim3(128, 6), 256, 0, stream>>>(a6, slots);

  QIW qiw;
  qiw.xq = inputs_q; qiw.xkv = inputs_kv; qiw.xqo = xq_b; qiw.xkvo = xkv_b;
  qiw.w[0] = Wq; qiw.wt[0] = wq_b;
  qiw.w[1] = Wk; qiw.wt[1] = wk_b;
  qiw.w[2] = Wv; qiw.wt[2] = wv_b;
  qiw.w[3] = Wo; qiw.wt[3] = wo_b;
  quantIW_kernel<<<dim3(512, 1, 6), 256, 0, stream>>>(qiw, slots, n8_x);

  G3 g3;
  g3.A[0] = xq_b;  g3.Bt[0] = wq_b; g3.bias[0] = bq; g3.C[0] = tf0;
  g3.A[1] = xkv_b; g3.Bt[1] = wk_b; g3.bias[1] = bk; g3.C[1] = tf1;
  g3.A[2] = xkv_b; g3.Bt[2] = wv_b; g3.bias[2] = bv; g3.C[2] = tf2;
  gemm3_kernel<<<dim3(256, 3), 256, 0, stream>>>(g3, slots);

  QP3 qp3;
  qp3.tf[0] = tf0; qp3.tf[1] = tf1; qp3.tf[2] = tf2;
  quantP3_kernel<<<dim3(1024, 1, 3), 256, 0, stream>>>(qp3, slots, q_p, k_p, vT_b);

  attn_kernel<<<512, 256, 0, stream>>>(q_p, k_p, vT_b, slots, rel, aof, slots + 9);

  quantize_bf16_kernel<<<1024, 256, 0, stream>>>(aof, n8_x, slots + 9, ao_b);

  gemm_wide_kernel<<<256, 256, 0, stream>>>(ao_b, wo_b, slots + 9, slots + 5, bo, out);
}